// Round 2
// 3125.206 us; speedup vs baseline: 1.9518x; 1.9518x over previous
//
#include <hip/hip_runtime.h>
#include <math.h>

// ESN: 512 sequential steps of h = tanh([h | x_t] @ [W_hh|W_ih]^T + b)
// T=512, B=64, I=128, H=1024, K' = 1152.
//
// R6 = R5 with the inline-asm input constraint fixed (float4 input -> clang
// ext_vector_type(4), hipcc can't pass HIP float4 structs as 'v' asm inputs).
//
// R5 (from R4 @ 6.1 ms): attack the per-step barrier latency (~9 of 11.9 us).
//  * W (18 float4/thread) + bias hoisted OUT of the t-loop -> resident in
//    VGPRs for all 512 steps. Removes 147 KB/WG/step of L2 reads.
//  * No buffer_wbl2: epilogue h/out stores are write-through (sc0 sc1) and
//    drained with vmcnt(0) per storing thread before __syncthreads, so the
//    flag release is a single sc0 sc1 dword store (data already at the
//    coherence point). Replaces __hip_atomic_store(RELEASE, AGENT).
//  * Sub-barriers: dependence is block-diagonal over bgrp (WG reads h rows
//    b0..b0+7 produced only by the 32 WGs with the same bgrp). 8 independent
//    32-wide barriers instead of one 256-wide one: straggler fan-in 256->32,
//    groups slip freely.
//  * x_t row prefetched one step ahead with a plain cached load (read-only
//    data), removing the second staging vmcnt(0) stall.

#define T_STEPS 512
#define BATCH   64
#define HDIM    1024
#define IDIM    128
#define KDIM    1152
#define NWG     256
#define NB      8

typedef float f32x4_t __attribute__((ext_vector_type(4)));

__device__ __forceinline__ unsigned sc_load(const unsigned* p) {
    unsigned v;
    asm volatile("global_load_dword %0, %1, off sc0 sc1\n\ts_waitcnt vmcnt(0)"
                 : "=&v"(v) : "v"(p) : "memory");
    return v;
}

__device__ __forceinline__ void sc_load4x4(const float* p0, const float* p1,
                                           const float* p2, const float* p3,
                                           float4& a, float4& b,
                                           float4& c, float4& d) {
    asm volatile(
        "global_load_dwordx4 %0, %4, off sc0 sc1\n\t"
        "global_load_dwordx4 %1, %5, off sc0 sc1\n\t"
        "global_load_dwordx4 %2, %6, off sc0 sc1\n\t"
        "global_load_dwordx4 %3, %7, off sc0 sc1\n\t"
        "s_waitcnt vmcnt(0)"
        : "=&v"(a), "=&v"(b), "=&v"(c), "=&v"(d)
        : "v"(p0), "v"(p1), "v"(p2), "v"(p3)
        : "memory");
}

// write-through store to the coherence point + drain: after this retires the
// data is visible to sc0/sc1 readers on any XCD (no wbl2 needed).
__device__ __forceinline__ void sc_store4(float* p, float4 v) {
    f32x4_t t;
    t.x = v.x; t.y = v.y; t.z = v.z; t.w = v.w;
    asm volatile("global_store_dwordx4 %0, %1, off sc0 sc1\n\ts_waitcnt vmcnt(0)"
                 :: "v"(p), "v"(t) : "memory");
}

__device__ __forceinline__ void flag_store(unsigned* p, unsigned v) {
    asm volatile("global_store_dword %0, %1, off sc0 sc1"
                 :: "v"(p), "v"(v) : "memory");
}

// 32-wide sub-barrier over the WGs of one bgrp. Data stores were already
// drained write-through by their issuing threads, so arrive = plain sc flag
// store after __syncthreads.
__device__ __forceinline__ void group_barrier(unsigned* flags, int wg, int bgrp,
                                              int tid, unsigned tgt) {
    __syncthreads();   // all epilogue threads have drained their sc stores
    if (tid == 0)
        flag_store(&flags[wg * 32], tgt);
    if (tid < 32)
        while (sc_load(&flags[(bgrp * 32 + tid) * 32]) < tgt) {}
    __syncthreads();
}

// src[R][C] -> dst[C][R], 64x64 LDS tiles, grid = (C/64)*(R/64), 256 thr
__global__ void transpose_f32(const float* __restrict__ src, float* __restrict__ dst,
                              int R, int C) {
    __shared__ float tile[64][65];
    const int tcol = threadIdx.x & 63;
    const int trow = threadIdx.x >> 6;
    const int nbx = C >> 6;
    const int bx = blockIdx.x % nbx;
    const int by = blockIdx.x / nbx;
    const int c0 = bx << 6, r0 = by << 6;
    for (int i = trow; i < 64; i += 4)
        tile[i][tcol] = src[(size_t)(r0 + i) * C + c0 + tcol];
    __syncthreads();
    for (int i = trow; i < 64; i += 4)
        dst[(size_t)(c0 + i) * R + r0 + tcol] = tile[tcol][i];
}

__global__ __launch_bounds__(512) void esn_persistent(
    const float* __restrict__ x,     // [512][64][128]
    const float* __restrict__ h0,    // [64][1024]
    const float* __restrict__ WT,    // [1152][1024]
    const float* __restrict__ bias,  // [1024]
    float* __restrict__ out,         // [512][64][1024]
    float* __restrict__ hfin,        // [64][1024]
    unsigned* flags)
{
    const int tid  = threadIdx.x;
    const int wg   = blockIdx.x;
    const int wave = tid >> 6;                       // 0..7 (k-slice / stage-row)
    const int lane = tid & 63;
    const int jq   = lane & 7;                       // 4 j each -> 32 j
    const int ksub = lane >> 3;                      // 0..7 k-interleave
    const int jblk = ((wg & 7) << 2) | ((wg >> 3) & 3);  // XCD owns 4 jblks
    const int bgrp = wg >> 5;                            // 0..7
    const int b0   = bgrp << 3;
    const int j0   = (jblk << 5) + (jq << 2);
    const int krec = wave << 7;                      // recurrent k base (128/wave)
    const int kx   = HDIM + (wave << 4) + (ksub << 1);  // x-part rows (2 each)

    __shared__ float  ht[NB][KDIM];                  // 36.9 KB row-major
    __shared__ float4 red[8 * 8 * 9];                // [w][jq] stride 9, +b pad

    // ---- hoist all 18 W float4 loads for ALL 512 steps (72 VGPRs) ----
    float4 Wv[18];
    {
        const float* wp = WT + (size_t)krec * HDIM + j0;
        #pragma unroll
        for (int i = 0; i < 4; ++i) {
            const int kk = ((i << 3) + ksub) << 2;      // 0..124 step 4
            const float* wk = wp + (size_t)kk * HDIM;
            Wv[i * 4 + 0] = *(const float4*)(wk);
            Wv[i * 4 + 1] = *(const float4*)(wk + HDIM);
            Wv[i * 4 + 2] = *(const float4*)(wk + 2 * HDIM);
            Wv[i * 4 + 3] = *(const float4*)(wk + 3 * HDIM);
        }
        const float* wkx = WT + (size_t)kx * HDIM + j0;
        Wv[16] = *(const float4*)(wkx);
        Wv[17] = *(const float4*)(wkx + HDIM);
    }

    // ---- hoist epilogue constants (bias, output column) ----
    float4 b4 = make_float4(0.f, 0.f, 0.f, 0.f);
    int jj = 0, bb_ep = 0;
    if (tid < 64) {
        bb_ep = tid >> 3;
        jj = (jblk << 5) + ((tid & 7) << 2);
        b4 = *(const float4*)(bias + jj);
    }

    // ---- prefetch x row for t=0 (plain cached load, x is read-only) ----
    float4 xv = make_float4(0.f, 0.f, 0.f, 0.f);
    if (lane < 32)
        xv = *(const float4*)(x + (size_t)(b0 + wave) * IDIM + (lane << 2));

    for (int t = 0; t < T_STEPS; ++t) {
        // ---- stage [h_{t-1} | x_t] row (b0+wave) into LDS ----
        const float* hrow = t ? (out + ((size_t)(t - 1) * BATCH + b0 + wave) * HDIM)
                              : (h0 + (size_t)(b0 + wave) * HDIM);
        {
            float4 a, b, c, d;
            const float* p = hrow + (lane << 2);
            sc_load4x4(p, p + 256, p + 512, p + 768, a, b, c, d);
            *(float4*)&ht[wave][(lane << 2)]       = a;
            *(float4*)&ht[wave][256 + (lane << 2)] = b;
            *(float4*)&ht[wave][512 + (lane << 2)] = c;
            *(float4*)&ht[wave][768 + (lane << 2)] = d;
        }
        if (lane < 32)
            *(float4*)&ht[wave][HDIM + (lane << 2)] = xv;
        __syncthreads();

        // prefetch next x row; latency hides under the FMA phase
        if (t + 1 < T_STEPS && lane < 32)
            xv = *(const float4*)(x + ((size_t)(t + 1) * BATCH + b0 + wave) * IDIM
                                  + (lane << 2));

        // ---- FMA: acc[b] over this thread's k (W already in registers) ----
        float4 acc[NB];
        #pragma unroll
        for (int bb = 0; bb < NB; ++bb) acc[bb] = make_float4(0.f, 0.f, 0.f, 0.f);

        #pragma unroll
        for (int i = 0; i < 4; ++i) {
            const int kk = krec + ((((i << 3) + ksub)) << 2);
            const float4 w0 = Wv[i * 4 + 0], w1 = Wv[i * 4 + 1];
            const float4 w2 = Wv[i * 4 + 2], w3 = Wv[i * 4 + 3];
            #pragma unroll
            for (int bb = 0; bb < NB; ++bb) {
                float4 h4 = *(const float4*)&ht[bb][kk];
                acc[bb].x = fmaf(w0.x, h4.x, acc[bb].x);
                acc[bb].y = fmaf(w0.y, h4.x, acc[bb].y);
                acc[bb].z = fmaf(w0.z, h4.x, acc[bb].z);
                acc[bb].w = fmaf(w0.w, h4.x, acc[bb].w);
                acc[bb].x = fmaf(w1.x, h4.y, acc[bb].x);
                acc[bb].y = fmaf(w1.y, h4.y, acc[bb].y);
                acc[bb].z = fmaf(w1.z, h4.y, acc[bb].z);
                acc[bb].w = fmaf(w1.w, h4.y, acc[bb].w);
                acc[bb].x = fmaf(w2.x, h4.z, acc[bb].x);
                acc[bb].y = fmaf(w2.y, h4.z, acc[bb].y);
                acc[bb].z = fmaf(w2.z, h4.z, acc[bb].z);
                acc[bb].w = fmaf(w2.w, h4.z, acc[bb].w);
                acc[bb].x = fmaf(w3.x, h4.w, acc[bb].x);
                acc[bb].y = fmaf(w3.y, h4.w, acc[bb].y);
                acc[bb].z = fmaf(w3.z, h4.w, acc[bb].z);
                acc[bb].w = fmaf(w3.w, h4.w, acc[bb].w);
            }
        }
        // x tail: 2 k per thread
        #pragma unroll
        for (int bb = 0; bb < NB; ++bb) {
            float2 hx = *(const float2*)&ht[bb][kx];
            acc[bb].x = fmaf(Wv[16].x, hx.x, acc[bb].x);
            acc[bb].y = fmaf(Wv[16].y, hx.x, acc[bb].y);
            acc[bb].z = fmaf(Wv[16].z, hx.x, acc[bb].z);
            acc[bb].w = fmaf(Wv[16].w, hx.x, acc[bb].w);
            acc[bb].x = fmaf(Wv[17].x, hx.y, acc[bb].x);
            acc[bb].y = fmaf(Wv[17].y, hx.y, acc[bb].y);
            acc[bb].z = fmaf(Wv[17].z, hx.y, acc[bb].z);
            acc[bb].w = fmaf(Wv[17].w, hx.y, acc[bb].w);
        }

        // ---- reduce over ksub (lane bits 3,4,5) ----
        #pragma unroll
        for (int bb = 0; bb < NB; ++bb) {
            acc[bb].x += __shfl_xor(acc[bb].x, 8);
            acc[bb].y += __shfl_xor(acc[bb].y, 8);
            acc[bb].z += __shfl_xor(acc[bb].z, 8);
            acc[bb].w += __shfl_xor(acc[bb].w, 8);
            acc[bb].x += __shfl_xor(acc[bb].x, 16);
            acc[bb].y += __shfl_xor(acc[bb].y, 16);
            acc[bb].z += __shfl_xor(acc[bb].z, 16);
            acc[bb].w += __shfl_xor(acc[bb].w, 16);
            acc[bb].x += __shfl_xor(acc[bb].x, 32);
            acc[bb].y += __shfl_xor(acc[bb].y, 32);
            acc[bb].z += __shfl_xor(acc[bb].z, 32);
            acc[bb].w += __shfl_xor(acc[bb].w, 32);
        }
        if (ksub == 0) {
            #pragma unroll
            for (int bb = 0; bb < NB; ++bb)
                red[((wave << 3) + jq) * 9 + bb] = acc[bb];
        }
        __syncthreads();

        // ---- cross-wave sum + tanh + write-through store (64 threads) ----
        if (tid < 64) {
            float4 s = make_float4(0.f, 0.f, 0.f, 0.f);
            #pragma unroll
            for (int w = 0; w < 8; ++w) {
                float4 r = red[((w << 3) + (tid & 7)) * 9 + bb_ep];
                s.x += r.x; s.y += r.y; s.z += r.z; s.w += r.w;
            }
            float4 o;
            o.x = tanhf(s.x + b4.x);
            o.y = tanhf(s.y + b4.y);
            o.z = tanhf(s.z + b4.z);
            o.w = tanhf(s.w + b4.w);
            // sc0 sc1 write-through + vmcnt(0): at the coherence point before
            // this thread reaches the barrier's __syncthreads
            sc_store4(out + ((size_t)t * BATCH + b0 + bb_ep) * HDIM + jj, o);
            if (t == T_STEPS - 1)
                *(float4*)(hfin + (size_t)(b0 + bb_ep) * HDIM + jj) = o;
        }

        if (t != T_STEPS - 1)
            group_barrier(flags, wg, bgrp, tid, (unsigned)(t + 1));
    }
}

extern "C" void kernel_launch(void* const* d_in, const int* in_sizes, int n_in,
                              void* d_out, int out_size, void* d_ws, size_t ws_size,
                              hipStream_t stream) {
    const float* x    = (const float*)d_in[0];
    const float* h0   = (const float*)d_in[1];
    const float* w_ih = (const float*)d_in[2];   // [1024][128]
    const float* w_hh = (const float*)d_in[3];   // [1024][1024]
    const float* bias = (const float*)d_in[4];   // [1024]
    float* out = (float*)d_out;

    char* ws = (char*)d_ws;
    float*    WT    = (float*)ws;                // [1152][1024] = 4.72 MB
    unsigned* flags = (unsigned*)(ws + 4718592); // 256 x 128 B

    (void)hipMemsetAsync(flags, 0, 32768, stream);
    transpose_f32<<<256, 256, 0, stream>>>(w_hh, WT, HDIM, HDIM);
    transpose_f32<<<32, 256, 0, stream>>>(w_ih, WT + (size_t)HDIM * HDIM, HDIM, IDIM);
    esn_persistent<<<NWG, 512, 0, stream>>>(x, h0, WT, bias,
                                            out, out + (size_t)T_STEPS * BATCH * HDIM,
                                            flags);
}